// Round 11
// baseline (226.219 us; speedup 1.0000x reference)
//
#include <hip/hip_runtime.h>

// Performer (FAVOR+) attention, MI355X bf16-MFMA implementation.
// Round 11: GEMM tile 256^2 -> 128^2 (BK=64, 4 waves, 64 KiB LDS) so TWO
// blocks co-reside per CU (m114 cross-block overlap absorbs the per-tile
// barrier/vmcnt convoy that capped the 1-block/CU 256^2 at 42% MfmaUtil).
// Same proven pieces: swz LDS swizzle (0 conflicts), 1-barrier free-run
// K-loop, coalesced scalar epilogue, T1 XCD swizzle, fused prep (R10).

typedef __attribute__((ext_vector_type(8))) short s8v;   // 8 x bf16 (4 VGPR)
typedef __attribute__((ext_vector_type(4))) short s4v;   // 4 x bf16
typedef __attribute__((ext_vector_type(4))) float f4v;   // MFMA acc
typedef __attribute__((ext_vector_type(4))) int   i4v;   // 16B chunk

#define MFMA16(a, b, c) __builtin_amdgcn_mfma_f32_16x16x32_bf16((a), (b), (c), 0, 0, 0)

__device__ __forceinline__ unsigned short f2bf(float f) {
  unsigned int u = __builtin_bit_cast(unsigned int, f);
  unsigned int r = (u + 0x7FFFu + ((u >> 16) & 1u)) >> 16;  // RNE
  return (unsigned short)r;
}

__device__ __forceinline__ int swz(int p) {          // involution, bits 7..9 -> 4..6
  return p ^ (((p >> 7) & 7) << 4);
}

__device__ __forceinline__ void gl_lds16(const void* g, void* l) {
  __builtin_amdgcn_global_load_lds(
      (const __attribute__((address_space(1))) void*)g,
      (__attribute__((address_space(3))) void*)l, 16, 0, 0);
}

// ---------------------------------------------------------------- prep (fused)
// blocks [0,16384): x f32 -> xb bf16.  [16384,19456): W_qkv^T.
// [19456,20480): W_out^T.  [20480,20544): RF^T per head.
__global__ __launch_bounds__(256) void prep_all(const float* __restrict__ x,
                                                unsigned short* __restrict__ xb,
                                                const float* __restrict__ W_qkv,
                                                unsigned short* __restrict__ wqkvt,
                                                const float* __restrict__ W_out,
                                                unsigned short* __restrict__ woutt,
                                                const float* __restrict__ RF,
                                                unsigned short* __restrict__ rft) {
  const int b = blockIdx.x, t = threadIdx.x;
  __shared__ float tile[32][33];
  if (b < 16384) {  // cvt path
    int i = b * 256 + t;
    f4v v = ((const f4v*)x)[i];
    s4v o;
#pragma unroll
    for (int j = 0; j < 4; ++j) o[j] = (short)f2bf(v[j]);
    ((s4v*)xb)[i] = o;
    return;
  }
  const float* in;
  unsigned short* out;
  int R, C, bx, by;
  if (b < 19456) {
    int idx = b - 16384;
    in = W_qkv; out = wqkvt; R = 1024; C = 3072; bx = idx % 96; by = idx / 96;
  } else if (b < 20480) {
    int idx = b - 19456;
    in = W_out; out = woutt; R = 1024; C = 1024; bx = idx & 31; by = idx >> 5;
  } else {
    int idx = b - 20480;
    in = RF + (idx >> 2) * 4096; out = rft + (idx >> 2) * 4096;
    R = 64; C = 64; bx = idx & 1; by = (idx >> 1) & 1;
  }
  const int tx = t & 31, ty = t >> 5;
  const int c0 = bx * 32, r0 = by * 32;
#pragma unroll
  for (int j = 0; j < 4; ++j)
    tile[ty + j * 8][tx] = in[(size_t)(r0 + ty + j * 8) * C + c0 + tx];
  __syncthreads();
#pragma unroll
  for (int j = 0; j < 4; ++j)
    out[(size_t)(c0 + ty + j * 8) * R + r0 + tx] = f2bf(tile[tx][ty + j * 8]);
}

// ---------------------------------------------------------------- GEMM 128x128
// C[M,N] = A[M,K] @ Bt[N,K]^T.  BK=64, 256 threads (4 waves, 2Mx2N),
// 64 KiB LDS = 2 dbuf x {A,B} x [128 rows][64 cols] bf16 -> 2 blocks/CU.
// Swizzle p ^= ((p>>7)&7)<<4 (inverse-swizzled global src + swizzled read).
// One barrier + one vmcnt(0) per K-tile (R7 free-run; WAR-safe: every
// ds_read is consumed by an MFMA before the wave's next barrier arrival).
template <int MODE>
__global__ __launch_bounds__(256, 2) void gemm128(const unsigned short* __restrict__ A,
                                                  const unsigned short* __restrict__ Bt,
                                                  void* __restrict__ Cout,
                                                  const float* __restrict__ bias,
                                                  int Nn, int K, int NTN, int CPX) {
  __shared__ __align__(128) unsigned short smem[32768];  // 64 KiB
  const int t = threadIdx.x, w = t >> 6, lane = t & 63;
  const int wm = w >> 1, wn = w & 1;
  const int fr = lane & 15, c16 = (lane >> 4) * 16;
  const int nkt = K >> 6;

  // T1: XCD-bijective block swizzle (grid % 8 == 0)
  const int bid = blockIdx.x;
  const int wg = (bid & 7) * CPX + (bid >> 3);
  const int tm = wg / NTN, tn = wg % NTN;

  const unsigned short* gA = A + (size_t)tm * 128 * K;
  const unsigned short* gB = Bt + (size_t)tn * 128 * K;

  // per-thread inverse-swizzled global source offsets (4 loads per matrix)
  int goffs[4];
#pragma unroll
  for (int i = 0; i < 4; ++i) {
    int o = (w * 4 + i) * 1024 + lane * 16;  // linear byte off in 16KB region
    int s = swz(o);
    goffs[i] = (s >> 7) * K + ((s & 127) >> 1);
  }

  auto stage = [&](int T2) {
    if (T2 >= nkt) return;
    char* bufA = (char*)smem + (T2 & 1) * 32768;  // 16KB A region
    char* bufB = bufA + 16384;                    // 16KB B region
    const unsigned short* gpA = gA + T2 * 64;
    const unsigned short* gpB = gB + T2 * 64;
#pragma unroll
    for (int i = 0; i < 4; ++i) {
      gl_lds16(gpA + goffs[i], bufA + (w * 4 + i) * 1024);
      gl_lds16(gpB + goffs[i], bufB + (w * 4 + i) * 1024);
    }
  };

  f4v acc[4][4] = {};
  stage(0);  // waited at top of T=0 (one-time exposed latency)

  for (int T = 0; T < nkt; ++T) {
    const char* Ar = (const char*)smem + (T & 1) * 32768;
    const char* Br = Ar + 16384;
    // tile-top: my loads for tile T landed -> barrier -> everyone's landed.
    asm volatile("s_waitcnt vmcnt(0)" ::: "memory");
    __builtin_amdgcn_s_barrier();
    __builtin_amdgcn_sched_barrier(0);
    stage(T + 1);  // prefetch into buffer d^1 (WAR-safe per header)
    s8v a[4][2], b[4][2];
#pragma unroll
    for (int i = 0; i < 4; ++i)
#pragma unroll
      for (int ks = 0; ks < 2; ++ks) {
        a[i][ks] = *(const s8v*)(Ar + swz((wm * 64 + i * 16 + fr) * 128 + ks * 64 + c16));
        b[i][ks] = *(const s8v*)(Br + swz((wn * 64 + i * 16 + fr) * 128 + ks * 64 + c16));
      }
    __builtin_amdgcn_s_setprio(1);
#pragma unroll
    for (int m = 0; m < 4; ++m)
#pragma unroll
      for (int n = 0; n < 4; ++n) {
        acc[m][n] = MFMA16(a[m][0], b[n][0], acc[m][n]);
        acc[m][n] = MFMA16(a[m][1], b[n][1], acc[m][n]);
      }
    __builtin_amdgcn_s_setprio(0);
  }

  // epilogue (row <-> a, col <-> b), coalesced row-major stores
#pragma unroll
  for (int m = 0; m < 4; ++m)
#pragma unroll
    for (int n = 0; n < 4; ++n) {
      const int row = tm * 128 + wm * 64 + m * 16 + (lane >> 4) * 4;
      const int col = tn * 128 + wn * 64 + n * 16 + fr;
      if (MODE == 0) {
        unsigned short* C = (unsigned short*)Cout;
#pragma unroll
        for (int r = 0; r < 4; ++r)
          C[(size_t)(row + r) * Nn + col] = f2bf(acc[m][n][r]);
      } else {
        float* C = (float*)Cout;
        const float bv = bias[col];
#pragma unroll
        for (int r = 0; r < 4; ++r)
          C[(size_t)(row + r) * Nn + col] = acc[m][n][r] + bv;
      }
    }
}

// ---------------------------------------------------------------- phi_k + kv
// block = (och, h, b); processes 512 tokens in 4 chunks of 128.
// kvpart[bh][och][80][64]: rows 0..63 = kv^T (d,r), row 64 = k_sum, 65..79 = 0.
__global__ __launch_bounds__(256) void phik_kv(const unsigned short* __restrict__ qkv,
                                               const unsigned short* __restrict__ RFt,
                                               float* __restrict__ kvpart) {
  __shared__ unsigned short RFl[2 * 64 * 32];   // [p][r][32]
  __shared__ unsigned short Kl[2 * 128 * 32];   // [p][n][32]
  __shared__ unsigned short pht[64 * 136];      // [r][n] (+pad)
  __shared__ unsigned short vt[80 * 136];       // [d][n] (+ones row 64)
  const int t = threadIdx.x, w = t >> 6, lane = t & 63;
  const int och = blockIdx.x, h = blockIdx.y, b = blockIdx.z;
  const int fr = lane & 15, kg = (lane >> 4) * 8;

#pragma unroll
  for (int i = 0; i < 2; ++i) {  // RF[h] -> RFl
    int unit = i * 256 + w * 64 + lane;
    int p = unit >> 8, rem = unit & 255;
    int r = rem >> 2, cg = (rem & 3) * 8;
    gl_lds16(RFt + ((h * 64 + r) * 64 + p * 32 + cg), &RFl[(i * 256 + w * 64) * 8]);
  }
  for (int i = t; i < 136; i += 256) vt[64 * 136 + i] = 0x3F80;     // ones row
  for (int i = t; i < 15 * 136; i += 256) vt[65 * 136 + i] = 0;     // zero pad rows

  f4v kvacc[5] = {};

  for (int c = 0; c < 4; ++c) {
    const int n0c = och * 512 + c * 128;
    const size_t rowbase = (size_t)(b * 4096 + n0c);
#pragma unroll
    for (int i = 0; i < 4; ++i) {  // K slice -> Kl
      int unit = i * 256 + w * 64 + lane;
      int p = unit >> 9, rem = unit & 511;
      int n = rem >> 2, cg = (rem & 3) * 8;
      gl_lds16(qkv + (rowbase + n) * 3072 + 1024 + h * 64 + p * 32 + cg,
               &Kl[(i * 256 + w * 64) * 8]);
    }
    i4v vreg[4];
#pragma unroll
    for (int it = 0; it < 4; ++it) {  // V slice -> regs
      int slot = it * 256 + t;
      vreg[it] = *(const i4v*)&qkv[(rowbase + (slot >> 3)) * 3072 + 2048 + h * 64 +
                                   (slot & 7) * 8];
    }
    __syncthreads();
    // phi_k = relu(K @ RF)
    f4v pacc[2][4] = {};
#pragma unroll
    for (int p = 0; p < 2; ++p) {
      s8v ka[2], rb[4];
#pragma unroll
      for (int m = 0; m < 2; ++m)
        ka[m] = *(const s8v*)&Kl[p * 4096 + (w * 32 + m * 16 + fr) * 32 + kg];
#pragma unroll
      for (int rf = 0; rf < 4; ++rf)
        rb[rf] = *(const s8v*)&RFl[p * 2048 + (rf * 16 + fr) * 32 + kg];
#pragma unroll
      for (int m = 0; m < 2; ++m)
#pragma unroll
        for (int rf = 0; rf < 4; ++rf)
          pacc[m][rf] = MFMA16(ka[m], rb[rf], pacc[m][rf]);
    }
    // v -> vt (transposed)
#pragma unroll
    for (int it = 0; it < 4; ++it) {
      int slot = it * 256 + t;
      int vn = slot >> 3, vdh = (slot & 7) * 8;
      const unsigned short* vr = (const unsigned short*)&vreg[it];
#pragma unroll
      for (int j = 0; j < 8; ++j) vt[(vdh + j) * 136 + vn] = vr[j];
    }
    // phi -> pht (transposed, relu, bf16)
#pragma unroll
    for (int m = 0; m < 2; ++m)
#pragma unroll
      for (int rf = 0; rf < 4; ++rf) {
        int r = rf * 16 + fr;
        int nb = w * 32 + m * 16 + (lane >> 4) * 4;
        s4v pk;
#pragma unroll
        for (int g = 0; g < 4; ++g) pk[g] = (short)f2bf(fmaxf(pacc[m][rf][g], 0.0f));
        *(s4v*)&pht[r * 136 + nb] = pk;
      }
    __syncthreads();
    // kv_aug[d][r] += vt @ pht^T  (wave w owns r-cols w*16..+15)
#pragma unroll
    for (int kst = 0; kst < 4; ++kst) {
      s8v pb = *(const s8v*)&pht[(w * 16 + fr) * 136 + kst * 32 + kg];
#pragma unroll
      for (int f = 0; f < 5; ++f) {
        s8v va = *(const s8v*)&vt[(f * 16 + fr) * 136 + kst * 32 + kg];
        kvacc[f] = MFMA16(va, pb, kvacc[f]);
      }
    }
  }
  const int bh = b * 16 + h;
  float* outp = kvpart + ((size_t)bh * 8 + och) * (80 * 64);
#pragma unroll
  for (int f = 0; f < 5; ++f) {
    int row = f * 16 + (lane >> 4) * 4;
    int col = w * 16 + fr;
#pragma unroll
    for (int g = 0; g < 4; ++g) outp[(row + g) * 64 + col] = kvacc[f][g];
  }
}

__global__ __launch_bounds__(256) void kv_reduce(const float* __restrict__ kvpart,
                                                 unsigned short* __restrict__ kvt) {
  const int bh = blockIdx.x, t = threadIdx.x;
  for (int i = t; i < 80 * 64; i += 256) {
    float s = 0.f;
#pragma unroll
    for (int c = 0; c < 8; ++c) s += kvpart[((size_t)bh * 8 + c) * 5120 + i];
    kvt[(size_t)bh * 5120 + i] = f2bf(s);
  }
}

// ---------------------------------------------------------------- phi_q + out
// block = (ch, h, b); 128 tokens. attno[token][h*64+d] = (phi_q@kv)/(phi_q.k_sum+eps)
__global__ __launch_bounds__(256) void phiq_out(const unsigned short* __restrict__ qkv,
                                                const unsigned short* __restrict__ RFt,
                                                const unsigned short* __restrict__ kvt,
                                                unsigned short* __restrict__ attno) {
  __shared__ unsigned short RFl[2 * 64 * 32];  // [p][r][32]
  __shared__ unsigned short Ql[2 * 128 * 32];  // [p][n][32]
  __shared__ unsigned short phl[128 * 72];     // [n][r] (+pad)
  __shared__ unsigned short kvl[80 * 72];      // [d][r] (+pad), row 64 = k_sum
  const int t = threadIdx.x, w = t >> 6, lane = t & 63;
  const int ch = blockIdx.x, h = blockIdx.y, b = blockIdx.z;
  const int fr = lane & 15, kg = (lane >> 4) * 8;
  const int bh = b * 16 + h;
  const size_t rowbase = (size_t)(b * 4096 + ch * 128);

#pragma unroll
  for (int i = 0; i < 2; ++i) {
    int unit = i * 256 + w * 64 + lane;
    int p = unit >> 8, rem = unit & 255;
    int r = rem >> 2, cg = (rem & 3) * 8;
    gl_lds16(RFt + ((h * 64 + r) * 64 + p * 32 + cg), &RFl[(i * 256 + w * 64) * 8]);
  }
#pragma unroll
  for (int i = 0; i < 4; ++i) {
    int unit = i * 256 + w * 64 + lane;
    int p = unit >> 9, rem = unit & 511;
    int n = rem >> 2, cg = (rem & 3) * 8;
    gl_lds16(qkv + (rowbase + n) * 3072 + h * 64 + p * 32 + cg,
             &Ql[(i * 256 + w * 64) * 8]);
  }
  for (int i = t; i < 640; i += 256) {  // kvt -> kvl (pad 64->72)
    int row = i >> 3, cg = (i & 7) * 8;
    *(i4v*)&kvl[row * 72 + cg] = *(const i4v*)&kvt[(size_t)bh * 5120 + row * 64 + cg];
  }
  __syncthreads();
  f4v pacc[2][4] = {};
#pragma unroll
  for (int p = 0; p < 2; ++p) {
    s8v qa[2], rb[4];
#pragma unroll
    for (int m = 0; m < 2; ++m)
      qa[m] = *(const s8v*)&Ql[p * 4096 + (w * 32 + m * 16 + fr) * 32 + kg];
#pragma unroll
    for (int rf = 0; rf < 4; ++rf)
      rb[rf] = *(const s8v*)&RFl[p * 2048 + (rf * 16 + fr) * 32 + kg];
#pragma unroll
    for (int m = 0; m < 2; ++m)
#pragma unroll
      for (int rf = 0; rf < 4; ++rf)
        pacc[m][rf] = MFMA16(qa[m], rb[rf], pacc[m][rf]);
  }
#pragma unroll
  for (int m = 0; m < 2; ++m)
#pragma unroll
    for (int rf = 0; rf < 4; ++rf) {
      int r = rf * 16 + fr;
      int nb = w * 32 + m * 16 + (lane >> 4) * 4;
#pragma unroll
      for (int g = 0; g < 4; ++g)
        phl[(nb + g) * 72 + r] = f2bf(fmaxf(pacc[m][rf][g], 0.0f));
    }
  __syncthreads();
  f4v acc[2][5] = {};
#pragma unroll
  for (int kst = 0; kst < 2; ++kst) {
    s8v pa[2], kb[5];
#pragma unroll
    for (int m = 0; m < 2; ++m)
      pa[m] = *(const s8v*)&phl[(w * 32 + m * 16 + fr) * 72 + kst * 32 + kg];
#pragma unroll
    for (int f = 0; f < 5; ++f)
      kb[f] = *(const s8v*)&kvl[(f * 16 + fr) * 72 + kst * 32 + kg];
#pragma unroll
    for (int m = 0; m < 2; ++m)
#pragma unroll
      for (int f = 0; f < 5; ++f) acc[m][f] = MFMA16(pa[m], kb[f], acc[m][f]);
  }
#pragma unroll
  for (int m = 0; m < 2; ++m)
#pragma unroll
    for (int g = 0; g < 4; ++g) {
      float nrm = __shfl(acc[m][4][g], lane & 48) + 1e-6f;  // col 64 = phi_q.k_sum
      int n = w * 32 + m * 16 + (lane >> 4) * 4 + g;
      size_t orow = rowbase + n;
#pragma unroll
      for (int f = 0; f < 4; ++f)
        attno[orow * 1024 + h * 64 + f * 16 + fr] = f2bf(acc[m][f][g] / nrm);
    }
}

// ---------------------------------------------------------------- launch
extern "C" void kernel_launch(void* const* d_in, const int* in_sizes, int n_in,
                              void* d_out, int out_size, void* d_ws, size_t ws_size,
                              hipStream_t stream) {
  const float* x = (const float*)d_in[0];      // [4,4096,1024]
  const float* W_qkv = (const float*)d_in[1];  // [1024,3072]
  const float* RF = (const float*)d_in[2];     // [16,64,64]
  const float* W_out = (const float*)d_in[3];  // [1024,1024]
  const float* b_out = (const float*)d_in[4];  // [1024]
  float* out = (float*)d_out;                  // [4,4096,1024]

  char* ws = (char*)d_ws;
  size_t off = 0;
  auto alloc = [&](size_t bytes) -> void* {
    void* p = ws + off;
    off += (bytes + 255) & ~(size_t)255;
    return p;
  };
  unsigned short* xb = (unsigned short*)alloc(16384ull * 1024 * 2);
  unsigned short* wqkvt = (unsigned short*)alloc(3072ull * 1024 * 2);
  unsigned short* woutt = (unsigned short*)alloc(1024ull * 1024 * 2);
  unsigned short* rft = (unsigned short*)alloc(16ull * 64 * 64 * 2);
  unsigned short* qkv = (unsigned short*)alloc(16384ull * 3072 * 2);
  float* kvpart = (float*)alloc(64ull * 8 * 80 * 64 * 4);
  unsigned short* kvt = (unsigned short*)alloc(64ull * 80 * 64 * 2);
  unsigned short* attno = (unsigned short*)alloc(16384ull * 1024 * 2);

  // fused prep: cvt (16384 blocks) + W_qkv^T (3072) + W_out^T (1024) + RF^T (64)
  prep_all<<<20544, 256, 0, stream>>>(x, xb, W_qkv, wqkvt, W_out, woutt, RF, rft);

  // qkv = xb @ wqkvt^T : M=16384 (128 tiles) x N=3072 (24 tiles), grid 3072
  gemm128<0><<<3072, 256, 0, stream>>>(xb, wqkvt, qkv, nullptr, 3072, 1024, 24, 384);
  phik_kv<<<dim3(8, 16, 4), 256, 0, stream>>>(qkv, rft, kvpart);
  kv_reduce<<<64, 256, 0, stream>>>(kvpart, kvt);
  phiq_out<<<dim3(32, 16, 4), 256, 0, stream>>>(qkv, rft, kvt, attno);
  // out = attno @ woutt^T + b : M=16384 x N=1024 (8 tiles), grid 1024
  gemm128<1><<<1024, 256, 0, stream>>>(attno, woutt, out, b_out, 1024, 1024, 8, 128);
}

// Round 12
// 209.633 us; speedup vs baseline: 1.0791x; 1.0791x over previous
//
#include <hip/hip_runtime.h>

// Performer (FAVOR+) attention, MI355X bf16-MFMA implementation.
// Round 12: R10 base (best: 217.7us) + chunk-XOR LDS swizzle on the three
// transposed mid-kernel buffers. Derivation: vt[(row)*136+col] scalar
// transpose writes had bank = f(col) only (row term 8*68dw = 0 mod 32)
// -> 16-way conflict; pht/phl s4v/scalar transposed writes ~4-way.
// Fix: 16B-chunk index ^= (row>>3)&7 on write AND read (same involution,
// rule 21). vt ones/zero rows are permutation-invariant (linear init OK).
// GEMMs/prep/kv_reduce byte-identical to R10.

typedef __attribute__((ext_vector_type(8))) short s8v;   // 8 x bf16 (4 VGPR)
typedef __attribute__((ext_vector_type(4))) short s4v;   // 4 x bf16
typedef __attribute__((ext_vector_type(4))) float f4v;   // MFMA acc
typedef __attribute__((ext_vector_type(4))) int   i4v;   // 16B chunk

#define MFMA16(a, b, c) __builtin_amdgcn_mfma_f32_16x16x32_bf16((a), (b), (c), 0, 0, 0)

__device__ __forceinline__ unsigned short f2bf(float f) {
  unsigned int u = __builtin_bit_cast(unsigned int, f);
  unsigned int r = (u + 0x7FFFu + ((u >> 16) & 1u)) >> 16;  // RNE
  return (unsigned short)r;
}

__device__ __forceinline__ int swz(int p) {          // involution, bits 7..9 -> 4..6
  return p ^ (((p >> 7) & 7) << 4);
}

__device__ __forceinline__ void gl_lds16(const void* g, void* l) {
  __builtin_amdgcn_global_load_lds(
      (const __attribute__((address_space(1))) void*)g,
      (__attribute__((address_space(3))) void*)l, 16, 0, 0);
}

// ---------------------------------------------------------------- prep (fused)
// blocks [0,16384): x f32 -> xb bf16.  [16384,19456): W_qkv^T.
// [19456,20480): W_out^T.  [20480,20544): RF^T per head.
__global__ __launch_bounds__(256) void prep_all(const float* __restrict__ x,
                                                unsigned short* __restrict__ xb,
                                                const float* __restrict__ W_qkv,
                                                unsigned short* __restrict__ wqkvt,
                                                const float* __restrict__ W_out,
                                                unsigned short* __restrict__ woutt,
                                                const float* __restrict__ RF,
                                                unsigned short* __restrict__ rft) {
  const int b = blockIdx.x, t = threadIdx.x;
  __shared__ float tile[32][33];
  if (b < 16384) {  // cvt path
    int i = b * 256 + t;
    f4v v = ((const f4v*)x)[i];
    s4v o;
#pragma unroll
    for (int j = 0; j < 4; ++j) o[j] = (short)f2bf(v[j]);
    ((s4v*)xb)[i] = o;
    return;
  }
  const float* in;
  unsigned short* out;
  int R, C, bx, by;
  if (b < 19456) {
    int idx = b - 16384;
    in = W_qkv; out = wqkvt; R = 1024; C = 3072; bx = idx % 96; by = idx / 96;
  } else if (b < 20480) {
    int idx = b - 19456;
    in = W_out; out = woutt; R = 1024; C = 1024; bx = idx & 31; by = idx >> 5;
  } else {
    int idx = b - 20480;
    in = RF + (idx >> 2) * 4096; out = rft + (idx >> 2) * 4096;
    R = 64; C = 64; bx = idx & 1; by = (idx >> 1) & 1;
  }
  const int tx = t & 31, ty = t >> 5;
  const int c0 = bx * 32, r0 = by * 32;
#pragma unroll
  for (int j = 0; j < 4; ++j)
    tile[ty + j * 8][tx] = in[(size_t)(r0 + ty + j * 8) * C + c0 + tx];
  __syncthreads();
#pragma unroll
  for (int j = 0; j < 4; ++j)
    out[(size_t)(c0 + ty + j * 8) * R + r0 + tx] = f2bf(tile[tx][ty + j * 8]);
}

// ---------------------------------------------------------------- GEMM 256x256
// R10/R7 structure: 1 barrier + 1 vmcnt(0) per K-tile, swizzled LDS, 8 waves.
template <int MODE>
__global__ __launch_bounds__(512, 2) void gemm256(const unsigned short* __restrict__ A,
                                                  const unsigned short* __restrict__ Bt,
                                                  void* __restrict__ Cout,
                                                  const float* __restrict__ bias,
                                                  int Nn, int K, int NTN, int CPX) {
  __shared__ __align__(128) unsigned short smem[65536];  // 128 KiB
  const int t = threadIdx.x, w = t >> 6, lane = t & 63;
  const int wm = w >> 2, wn = w & 3;
  const int fr = lane & 15, c16 = (lane >> 4) * 16;
  const int nkt = K >> 6;

  const int bid = blockIdx.x;
  const int wg = (bid & 7) * CPX + (bid >> 3);
  const int tm = wg / NTN, tn = wg % NTN;

  const unsigned short* gA = A + (size_t)tm * 256 * K;
  const unsigned short* gB = Bt + (size_t)tn * 256 * K;

  const int s0 = swz(t * 16);
  const int s1 = swz(8192 + t * 16);
  const int goff0 = (s0 >> 7) * K + ((s0 & 127) >> 1);
  const int goff1 = ((s1 - 8192) >> 7) * K + ((s1 & 127) >> 1) + 64 * K;
  const int woff = w * 1024;

  auto stage = [&](int T2, int part) {
    if (T2 >= nkt) return;
    char* reg = (char*)smem + (((T2 & 1) * 4 + part) << 14);
    const unsigned short* gp =
        (part < 2 ? gA : gB) + (size_t)((part & 1) * 128) * K + T2 * 64;
    gl_lds16(gp + goff0, reg + woff);
    gl_lds16(gp + goff1, reg + 8192 + woff);
  };

  f4v acc[8][4] = {};
  stage(0, 0); stage(0, 1); stage(0, 2); stage(0, 3);

  auto rdA = [&](int mh, s8v (&a)[4][2], const char* Ar) {
#pragma unroll
    for (int i = 0; i < 4; ++i)
#pragma unroll
      for (int ks = 0; ks < 2; ++ks) {
        int p = swz((mh * 64 + i * 16 + fr) * 128 + ks * 64 + c16);
        a[i][ks] = *(const s8v*)(Ar + p);
      }
  };
  auto rdB = [&](int nh, s8v (&b)[2][2], const char* Br, int brow) {
#pragma unroll
    for (int j = 0; j < 2; ++j)
#pragma unroll
      for (int ks = 0; ks < 2; ++ks) {
        int p = swz((brow + nh * 32 + j * 16 + fr) * 128 + ks * 64 + c16);
        b[j][ks] = *(const s8v*)(Br + p);
      }
  };
  auto mmac = [&](int mh, int nh, const s8v (&a)[4][2], const s8v (&b)[2][2]) {
    __builtin_amdgcn_s_setprio(1);
#pragma unroll
    for (int i = 0; i < 4; ++i)
#pragma unroll
      for (int j = 0; j < 2; ++j) {
        acc[mh * 4 + i][nh * 2 + j] = MFMA16(a[i][0], b[j][0], acc[mh * 4 + i][nh * 2 + j]);
        acc[mh * 4 + i][nh * 2 + j] = MFMA16(a[i][1], b[j][1], acc[mh * 4 + i][nh * 2 + j]);
      }
    __builtin_amdgcn_s_setprio(0);
  };

  const int brow = (wn & 1) * 64;
  for (int T = 0; T < nkt; ++T) {
    const int d = T & 1;
    const char* Ar = (const char*)smem + ((d * 4 + wm) << 14);
    const char* Br = (const char*)smem + ((d * 4 + 2 + (wn >> 1)) << 14);
    asm volatile("s_waitcnt vmcnt(0)" ::: "memory");
    __builtin_amdgcn_s_barrier();
    __builtin_amdgcn_sched_barrier(0);
    stage(T + 1, 0); stage(T + 1, 1); stage(T + 1, 2); stage(T + 1, 3);
    s8v a[4][2], b0[2][2], b1[2][2];
    rdA(0, a, Ar); rdB(0, b0, Br, brow); rdB(1, b1, Br, brow);
    mmac(0, 0, a, b0);
    mmac(0, 1, a, b1);
    rdA(1, a, Ar);
    mmac(1, 1, a, b1);
    mmac(1, 0, a, b0);
  }

#pragma unroll
  for (int m = 0; m < 8; ++m)
#pragma unroll
    for (int n = 0; n < 4; ++n) {
      const int row = tm * 256 + wm * 128 + m * 16 + (lane >> 4) * 4;
      const int col = tn * 256 + wn * 64 + n * 16 + fr;
      if (MODE == 0) {
        unsigned short* C = (unsigned short*)Cout;
#pragma unroll
        for (int r = 0; r < 4; ++r)
          C[(size_t)(row + r) * Nn + col] = f2bf(acc[m][n][r]);
      } else {
        float* C = (float*)Cout;
        const float bv = bias[col];
#pragma unroll
        for (int r = 0; r < 4; ++r)
          C[(size_t)(row + r) * Nn + col] = acc[m][n][r] + bv;
      }
    }
}

// ---------------------------------------------------------------- phi_k + kv
// block = (och, h, b); 512 tokens in 4 chunks of 128.
// kvpart[bh][och][80][64]: rows 0..63 = kv^T (d,r), row 64 = k_sum, 65..79 = 0.
// vt/pht use 16B-chunk XOR swizzle: chunk ^= (row>>3)&7 (write & read).
__global__ __launch_bounds__(256) void phik_kv(const unsigned short* __restrict__ qkv,
                                               const unsigned short* __restrict__ RFt,
                                               float* __restrict__ kvpart) {
  __shared__ unsigned short RFl[2 * 64 * 32];   // [p][r][32]
  __shared__ unsigned short Kl[2 * 128 * 32];   // [p][n][32]
  __shared__ unsigned short pht[64 * 136];      // [r][n] swizzled (+pad)
  __shared__ unsigned short vt[80 * 136];       // [d][n] swizzled (+ones row 64)
  const int t = threadIdx.x, w = t >> 6, lane = t & 63;
  const int och = blockIdx.x, h = blockIdx.y, b = blockIdx.z;
  const int fr = lane & 15, kg = (lane >> 4) * 8;

#pragma unroll
  for (int i = 0; i < 2; ++i) {  // RF[h] -> RFl
    int unit = i * 256 + w * 64 + lane;
    int p = unit >> 8, rem = unit & 255;
    int r = rem >> 2, cg = (rem & 3) * 8;
    gl_lds16(RFt + ((h * 64 + r) * 64 + p * 32 + cg), &RFl[(i * 256 + w * 64) * 8]);
  }
  // ones row (64) and zero rows (65-79): values uniform per row ->
  // invariant under the chunk permutation; linear init is correct.
  for (int i = t; i < 136; i += 256) vt[64 * 136 + i] = 0x3F80;
  for (int i = t; i < 15 * 136; i += 256) vt[65 * 136 + i] = 0;

  f4v kvacc[5] = {};

  for (int c = 0; c < 4; ++c) {
    const int n0c = och * 512 + c * 128;
    const size_t rowbase = (size_t)(b * 4096 + n0c);
#pragma unroll
    for (int i = 0; i < 4; ++i) {  // K slice -> Kl
      int unit = i * 256 + w * 64 + lane;
      int p = unit >> 9, rem = unit & 511;
      int n = rem >> 2, cg = (rem & 3) * 8;
      gl_lds16(qkv + (rowbase + n) * 3072 + 1024 + h * 64 + p * 32 + cg,
               &Kl[(i * 256 + w * 64) * 8]);
    }
    i4v vreg[4];
#pragma unroll
    for (int it = 0; it < 4; ++it) {  // V slice -> regs
      int slot = it * 256 + t;
      vreg[it] = *(const i4v*)&qkv[(rowbase + (slot >> 3)) * 3072 + 2048 + h * 64 +
                                   (slot & 7) * 8];
    }
    __syncthreads();
    // phi_k = relu(K @ RF)
    f4v pacc[2][4] = {};
#pragma unroll
    for (int p = 0; p < 2; ++p) {
      s8v ka[2], rb[4];
#pragma unroll
      for (int m = 0; m < 2; ++m)
        ka[m] = *(const s8v*)&Kl[p * 4096 + (w * 32 + m * 16 + fr) * 32 + kg];
#pragma unroll
      for (int rf = 0; rf < 4; ++rf)
        rb[rf] = *(const s8v*)&RFl[p * 2048 + (rf * 16 + fr) * 32 + kg];
#pragma unroll
      for (int m = 0; m < 2; ++m)
#pragma unroll
        for (int rf = 0; rf < 4; ++rf)
          pacc[m][rf] = MFMA16(ka[m], rb[rf], pacc[m][rf]);
    }
    // v -> vt (transposed, chunk-XOR swizzled: key = (row>>3)&7 = slot&7)
#pragma unroll
    for (int it = 0; it < 4; ++it) {
      int slot = it * 256 + t;
      int vn = slot >> 3, key = slot & 7, vdh = key * 8;
      int cs = (((vn >> 3) ^ key) << 3) + (vn & 7);
      const unsigned short* vr = (const unsigned short*)&vreg[it];
#pragma unroll
      for (int j = 0; j < 8; ++j) vt[(vdh + j) * 136 + cs] = vr[j];
    }
    // phi -> pht (transposed, relu, bf16, chunk-XOR swizzled)
#pragma unroll
    for (int m = 0; m < 2; ++m)
#pragma unroll
      for (int rf = 0; rf < 4; ++rf) {
        int r = rf * 16 + fr;
        int nb = w * 32 + m * 16 + (lane >> 4) * 4;
        int cs = (((nb >> 3) ^ ((r >> 3) & 7)) << 3) + (nb & 7);
        s4v pk;
#pragma unroll
        for (int g = 0; g < 4; ++g) pk[g] = (short)f2bf(fmaxf(pacc[m][rf][g], 0.0f));
        *(s4v*)&pht[r * 136 + cs] = pk;
      }
    __syncthreads();
    // kv_aug[d][r] += vt @ pht^T  (wave w owns r-cols w*16..+15)
#pragma unroll
    for (int kst = 0; kst < 4; ++kst) {
      const int ch = kst * 4 + (lane >> 4);  // 16B chunk of the k-slice
      const int prow = w * 16 + fr;
      s8v pb = *(const s8v*)&pht[prow * 136 + ((ch ^ ((prow >> 3) & 7)) << 3)];
#pragma unroll
      for (int f = 0; f < 5; ++f) {
        const int vrow = f * 16 + fr;
        s8v va = *(const s8v*)&vt[vrow * 136 + ((ch ^ ((vrow >> 3) & 7)) << 3)];
        kvacc[f] = MFMA16(va, pb, kvacc[f]);
      }
    }
  }
  const int bh = b * 16 + h;
  float* outp = kvpart + ((size_t)bh * 8 + och) * (80 * 64);
#pragma unroll
  for (int f = 0; f < 5; ++f) {
    int row = f * 16 + (lane >> 4) * 4;
    int col = w * 16 + fr;
#pragma unroll
    for (int g = 0; g < 4; ++g) outp[(row + g) * 64 + col] = kvacc[f][g];
  }
}

__global__ __launch_bounds__(256) void kv_reduce(const float* __restrict__ kvpart,
                                                 unsigned short* __restrict__ kvt) {
  const int bh = blockIdx.x, t = threadIdx.x;
  for (int i = t; i < 80 * 64; i += 256) {
    float s = 0.f;
#pragma unroll
    for (int c = 0; c < 8; ++c) s += kvpart[((size_t)bh * 8 + c) * 5120 + i];
    kvt[(size_t)bh * 5120 + i] = f2bf(s);
  }
}

// ---------------------------------------------------------------- phi_q + out
// block = (ch, h, b); 128 tokens. phl uses the same chunk-XOR swizzle.
__global__ __launch_bounds__(256) void phiq_out(const unsigned short* __restrict__ qkv,
                                                const unsigned short* __restrict__ RFt,
                                                const unsigned short* __restrict__ kvt,
                                                unsigned short* __restrict__ attno) {
  __shared__ unsigned short RFl[2 * 64 * 32];  // [p][r][32]
  __shared__ unsigned short Ql[2 * 128 * 32];  // [p][n][32]
  __shared__ unsigned short phl[128 * 72];     // [n][r] swizzled (+pad)
  __shared__ unsigned short kvl[80 * 72];      // [d][r] (+pad), row 64 = k_sum
  const int t = threadIdx.x, w = t >> 6, lane = t & 63;
  const int ch = blockIdx.x, h = blockIdx.y, b = blockIdx.z;
  const int fr = lane & 15, kg = (lane >> 4) * 8;
  const int bh = b * 16 + h;
  const size_t rowbase = (size_t)(b * 4096 + ch * 128);

#pragma unroll
  for (int i = 0; i < 2; ++i) {
    int unit = i * 256 + w * 64 + lane;
    int p = unit >> 8, rem = unit & 255;
    int r = rem >> 2, cg = (rem & 3) * 8;
    gl_lds16(RFt + ((h * 64 + r) * 64 + p * 32 + cg), &RFl[(i * 256 + w * 64) * 8]);
  }
#pragma unroll
  for (int i = 0; i < 4; ++i) {
    int unit = i * 256 + w * 64 + lane;
    int p = unit >> 9, rem = unit & 511;
    int n = rem >> 2, cg = (rem & 3) * 8;
    gl_lds16(qkv + (rowbase + n) * 3072 + h * 64 + p * 32 + cg,
             &Ql[(i * 256 + w * 64) * 8]);
  }
  for (int i = t; i < 640; i += 256) {  // kvt -> kvl (pad 64->72)
    int row = i >> 3, cg = (i & 7) * 8;
    *(i4v*)&kvl[row * 72 + cg] = *(const i4v*)&kvt[(size_t)bh * 5120 + row * 64 + cg];
  }
  __syncthreads();
  f4v pacc[2][4] = {};
#pragma unroll
  for (int p = 0; p < 2; ++p) {
    s8v qa[2], rb[4];
#pragma unroll
    for (int m = 0; m < 2; ++m)
      qa[m] = *(const s8v*)&Ql[p * 4096 + (w * 32 + m * 16 + fr) * 32 + kg];
#pragma unroll
    for (int rf = 0; rf < 4; ++rf)
      rb[rf] = *(const s8v*)&RFl[p * 2048 + (rf * 16 + fr) * 32 + kg];
#pragma unroll
    for (int m = 0; m < 2; ++m)
#pragma unroll
      for (int rf = 0; rf < 4; ++rf)
        pacc[m][rf] = MFMA16(qa[m], rb[rf], pacc[m][rf]);
  }
  // phi_q -> phl (transposed, relu, chunk-XOR swizzled on row key)
#pragma unroll
  for (int m = 0; m < 2; ++m)
#pragma unroll
    for (int rf = 0; rf < 4; ++rf) {
      int r = rf * 16 + fr;
      int nb = w * 32 + m * 16 + (lane >> 4) * 4;
#pragma unroll
      for (int g = 0; g < 4; ++g) {
        int row = nb + g;
        int cs = (((r >> 3) ^ ((row >> 3) & 7)) << 3) + (r & 7);
        phl[row * 72 + cs] = f2bf(fmaxf(pacc[m][rf][g], 0.0f));
      }
    }
  __syncthreads();
  f4v acc[2][5] = {};
#pragma unroll
  for (int kst = 0; kst < 2; ++kst) {
    const int chk = kst * 4 + (lane >> 4);
    s8v pa[2], kb[5];
#pragma unroll
    for (int m = 0; m < 2; ++m) {
      int row = w * 32 + m * 16 + fr;
      pa[m] = *(const s8v*)&phl[row * 72 + ((chk ^ ((row >> 3) & 7)) << 3)];
    }
#pragma unroll
    for (int f = 0; f < 5; ++f)
      kb[f] = *(const s8v*)&kvl[(f * 16 + fr) * 72 + kst * 32 + kg];
#pragma unroll
    for (int m = 0; m < 2; ++m)
#pragma unroll
      for (int f = 0; f < 5; ++f) acc[m][f] = MFMA16(pa[m], kb[f], acc[m][f]);
  }
#pragma unroll
  for (int m = 0; m < 2; ++m)
#pragma unroll
    for (int g = 0; g < 4; ++g) {
      float nrm = __shfl(acc[m][4][g], lane & 48) + 1e-6f;  // col 64 = phi_q.k_sum
      int n = w * 32 + m * 16 + (lane >> 4) * 4 + g;
      size_t orow = rowbase + n;
#pragma unroll
      for (int f = 0; f < 4; ++f)
        attno[orow * 1024 + h * 64 + f * 16 + fr] = f2bf(acc[m][f][g] / nrm);
    }
}

// ---------------------------------------------------------------- launch
extern "C" void kernel_launch(void* const* d_in, const int* in_sizes, int n_in,
                              void* d_out, int out_size, void* d_ws, size_t ws_size,
                              hipStream_t stream) {
  const float* x = (const float*)d_in[0];      // [4,4096,1024]
  const float* W_qkv = (const float*)d_in[1];  // [1024,3072]
  const float* RF = (const float*)d_in[2];     // [16,64,64]
  const float* W_out = (const float*)d_in[3];  // [1024,1024]
  const float* b_out = (const float*)d_in[4];  // [1024]
  float* out = (float*)d_out;                  // [4,4096,1024]

  char* ws = (char*)d_ws;
  size_t off = 0;
  auto alloc = [&](size_t bytes) -> void* {
    void* p = ws + off;
    off += (bytes + 255) & ~(size_t)255;
    return p;
  };
  unsigned short* xb = (unsigned short*)alloc(16384ull * 1024 * 2);
  unsigned short* wqkvt = (unsigned short*)alloc(3072ull * 1024 * 2);
  unsigned short* woutt = (unsigned short*)alloc(1024ull * 1024 * 2);
  unsigned short* rft = (unsigned short*)alloc(16ull * 64 * 64 * 2);
  unsigned short* qkv = (unsigned short*)alloc(16384ull * 3072 * 2);
  float* kvpart = (float*)alloc(64ull * 8 * 80 * 64 * 4);
  unsigned short* kvt = (unsigned short*)alloc(64ull * 80 * 64 * 2);
  unsigned short* attno = (unsigned short*)alloc(16384ull * 1024 * 2);

  // fused prep: cvt (16384 blocks) + W_qkv^T (3072) + W_out^T (1024) + RF^T (64)
  prep_all<<<20544, 256, 0, stream>>>(x, xb, W_qkv, wqkvt, W_out, woutt, RF, rft);

  // qkv = xb @ wqkvt^T : M=16384 (64 tiles) x N=3072 (12 tiles), grid 768
  gemm256<0><<<768, 512, 0, stream>>>(xb, wqkvt, qkv, nullptr, 3072, 1024, 12, 96);
  phik_kv<<<dim3(8, 16, 4), 256, 0, stream>>>(qkv, rft, kvpart);
  kv_reduce<<<64, 256, 0, stream>>>(kvpart, kvt);
  phiq_out<<<dim3(32, 16, 4), 256, 0, stream>>>(qkv, rft, kvt, attno);
  // out = attno @ woutt^T + b : M=16384 x N=1024 (4 tiles), grid 256
  gemm256<1><<<256, 512, 0, stream>>>(attno, woutt, out, b_out, 1024, 1024, 4, 32);
}